// Round 1
// baseline (158.879 us; speedup 1.0000x reference)
//
#include <hip/hip_runtime.h>
#include <hip/hip_bf16.h>
#include <math.h>

// ---------- helpers ----------
__device__ __forceinline__ float leaky(float x) { return x > 0.0f ? x : 0.01f * x; }

// ---------- kernel A: mean over HW of x_mid [128,512,28,28] -> [128,512] ----------
// one wave per (b,c) row of 784 contiguous floats (= 196 float4)
__global__ __launch_bounds__(256) void mean_mid_kernel(const float* __restrict__ x,
                                                       float* __restrict__ out)
{
    int tid  = threadIdx.x;
    int lane = tid & 63;
    int wid  = tid >> 6;                       // 0..3
    int row  = blockIdx.x * 4 + wid;           // 0..65535
    const float4* r = (const float4*)(x + (size_t)row * 784);
    float s = 0.0f;
    for (int i = lane; i < 196; i += 64) {
        float4 v = r[i];
        s += v.x + v.y + v.z + v.w;
    }
    #pragma unroll
    for (int off = 32; off; off >>= 1) s += __shfl_xor(s, off);
    if (lane == 0) out[row] = s * (1.0f / 784.0f);
}

// ---------- kernel B: mean over HW of x_deep [128,2048,7,7] -> [128,2048] ----------
// 16 lanes per row of 49 floats
__global__ __launch_bounds__(256) void mean_deep_kernel(const float* __restrict__ x,
                                                        float* __restrict__ out)
{
    int tid = threadIdx.x;
    int sub = tid & 15;
    int r   = tid >> 4;                        // 0..15
    int row = blockIdx.x * 16 + r;             // 0..262143
    const float* base = x + (size_t)row * 49;
    float s = base[sub] + base[sub + 16] + base[sub + 32];
    if (sub == 0) s += base[48];
    #pragma unroll
    for (int off = 8; off; off >>= 1) s += __shfl_xor(s, off);
    if (sub == 0) out[row] = s * (1.0f / 49.0f);
}

// ---------- generic split-K GEMM: C = A[128,K] * B[N,K]^T, partials to P ----------
// BM=128, BN=32, BK=32. grid = (N/32, S, paths). P layout: [path][s][128*N]
__global__ __launch_bounds__(256) void gemm_nt_splitk(
    const float* __restrict__ A0, const float* __restrict__ B0,
    const float* __restrict__ A1, const float* __restrict__ B1,
    float* __restrict__ P, int N, int K, int S)
{
    __shared__ float As[128][34];
    __shared__ float Bs[32][34];

    const int z  = blockIdx.z;
    const float* A = z ? A1 : A0;
    const float* B = z ? B1 : B0;
    const int n0 = blockIdx.x * 32;
    const int s  = blockIdx.y;
    const int Kc = K / S;                      // multiple of 32 for all layers
    const int k0 = s * Kc;
    float* Pb = P + ((size_t)(z * S + s)) * 128 * N;

    const int tid = threadIdx.x;
    const int tx = tid & 7;                    // n-group (8 groups x 4 cols)
    const int ty = tid >> 3;                   // m-group (32 groups x 4 rows)

    float acc[4][4] = {};

    for (int kt = k0; kt < k0 + Kc; kt += 32) {
        // stage A 128x32 (float4 global loads, scalar LDS stores)
        #pragma unroll
        for (int it = 0; it < 4; ++it) {
            int idx = it * 256 + tid;          // 0..1023
            int m = idx >> 3, kq = idx & 7;
            float4 v = *(const float4*)(A + (size_t)m * K + kt + kq * 4);
            As[m][kq * 4 + 0] = v.x; As[m][kq * 4 + 1] = v.y;
            As[m][kq * 4 + 2] = v.z; As[m][kq * 4 + 3] = v.w;
        }
        // stage B 32x32
        {
            int m = tid >> 3, kq = tid & 7;
            float4 v = *(const float4*)(B + (size_t)(n0 + m) * K + kt + kq * 4);
            Bs[m][kq * 4 + 0] = v.x; Bs[m][kq * 4 + 1] = v.y;
            Bs[m][kq * 4 + 2] = v.z; Bs[m][kq * 4 + 3] = v.w;
        }
        __syncthreads();

        #pragma unroll
        for (int kk = 0; kk < 32; kk += 2) {
            float2 a[4], b[4];
            #pragma unroll
            for (int i = 0; i < 4; ++i) a[i] = *(const float2*)&As[ty * 4 + i][kk];
            #pragma unroll
            for (int j = 0; j < 4; ++j) b[j] = *(const float2*)&Bs[tx * 4 + j][kk];
            #pragma unroll
            for (int i = 0; i < 4; ++i)
                #pragma unroll
                for (int j = 0; j < 4; ++j)
                    acc[i][j] += a[i].x * b[j].x + a[i].y * b[j].y;
        }
        __syncthreads();
    }

    #pragma unroll
    for (int i = 0; i < 4; ++i) {
        float4 v = { acc[i][0], acc[i][1], acc[i][2], acc[i][3] };
        *(float4*)(Pb + (size_t)(ty * 4 + i) * N + n0 + tx * 4) = v;
    }
}

// ---------- split-K reduce + optional leaky ----------
__global__ void reduce_act(const float* __restrict__ P, float* __restrict__ out0,
                           float* __restrict__ out1, int MN, int S, int paths, int do_act)
{
    int idx = blockIdx.x * blockDim.x + threadIdx.x;
    if (idx >= paths * MN) return;
    int z = idx / MN, e = idx - z * MN;
    const float* base = P + (size_t)z * S * MN;
    float s = 0.0f;
    for (int i = 0; i < S; ++i) s += base[(size_t)i * MN + e];
    if (do_act) s = leaky(s);
    float* o = z ? out1 : out0;
    o[e] = s;
}

// ---------- tail: texture MLP, sim/argmax/CE, class path, q path (per sample) ----------
__global__ __launch_bounds__(64) void tail_kernel(
    const float* __restrict__ s3, const float* __restrict__ o3,
    const float* __restrict__ tw1, const float* __restrict__ tw2,
    const float* __restrict__ cw1, const float* __restrict__ cw2,
    const float* __restrict__ qw1, const float* __restrict__ qw2,
    const float* __restrict__ center, const float* __restrict__ proto,
    float* __restrict__ ce_t, float* __restrict__ osv,
    float* __restrict__ csv, float* __restrict__ alv)
{
    const int b = blockIdx.x;
    const int o = threadIdx.x;                 // 0..63, one wave
    const float* sh  = s3 + b * 64;
    const float* org = o3 + b * 64;
    __shared__ float t1[64], c1[64], q1[64];

    // texture layer 1: in = [shallow, shallow - center]
    float acc = 0.0f;
    for (int j = 0; j < 64; ++j) acc += tw1[o * 128 + j] * sh[j];
    for (int j = 0; j < 64; ++j) acc += tw1[o * 128 + 64 + j] * (sh[j] - center[j]);
    t1[o] = leaky(acc);
    __syncthreads();
    acc = 0.0f;
    for (int j = 0; j < 64; ++j) acc += tw2[o * 64 + j] * t1[j];
    float tex = leaky(acc);

    // sim[k] = ||texture - proto_k||^2 (all-lane reduce)
    float sim[4];
    #pragma unroll
    for (int k = 0; k < 4; ++k) {
        float d = tex - proto[k * 64 + o];
        float v = d * d;
        #pragma unroll
        for (int off = 32; off; off >>= 1) v += __shfl_xor(v, off);
        sim[k] = v;
    }
    int cat = 0; float best = sim[0];
    #pragma unroll
    for (int k = 1; k < 4; ++k) if (sim[k] > best) { best = sim[k]; cat = k; }
    float sume = 0.0f;
    #pragma unroll
    for (int k = 0; k < 4; ++k) sume += expf(sim[k] - best);
    // ce term = logsumexp(sim) - sim[argmax] = log(sum exp(sim - max))

    // class path: in = [origin, origin - proto[cat]]
    acc = 0.0f;
    for (int j = 0; j < 64; ++j) acc += cw1[o * 128 + j] * org[j];
    for (int j = 0; j < 64; ++j) acc += cw1[o * 128 + 64 + j] * (org[j] - proto[cat * 64 + j]);
    c1[o] = leaky(acc);
    __syncthreads();
    acc = 0.0f;
    for (int j = 0; j < 64; ++j) acc += cw2[o * 64 + j] * c1[j];
    float cf = leaky(acc);
    float dc = cf - center[o];
    float cs = dc * dc;
    #pragma unroll
    for (int off = 32; off; off >>= 1) cs += __shfl_xor(cs, off);

    // q path
    acc = 0.0f;
    for (int j = 0; j < 64; ++j) acc += qw1[o * 64 + j] * org[j];
    q1[o] = leaky(acc);
    __syncthreads();
    acc = 0.0f;
    for (int j = 0; j < 64; ++j) acc += qw2[o * 64 + j] * q1[j];
    float qf = leaky(acc);
    float dq = qf - center[o];
    float os = dq * dq;
    #pragma unroll
    for (int off = 32; off; off >>= 1) os += __shfl_xor(os, off);

    if (o == 0) {
        ce_t[b] = logf(sume);
        osv[b]  = os;
        csv[b]  = cs;
        alv[b]  = fabsf(os - cs);
    }
}

// ---------- finalize: mean over 128 samples -> out[4] ----------
__global__ __launch_bounds__(128) void finalize_kernel(
    const float* __restrict__ ce_t, const float* __restrict__ osv,
    const float* __restrict__ csv, const float* __restrict__ alv,
    float* __restrict__ out)
{
    int t = threadIdx.x;                       // 0..127
    float v[4] = { ce_t[t], osv[t], csv[t], alv[t] };
    __shared__ float tmp[4][2];
    int lane = t & 63, w = t >> 6;
    #pragma unroll
    for (int i = 0; i < 4; ++i) {
        float x = v[i];
        #pragma unroll
        for (int off = 32; off; off >>= 1) x += __shfl_xor(x, off);
        if (lane == 0) tmp[i][w] = x;
    }
    __syncthreads();
    if (t < 4) out[t] = (tmp[t][0] + tmp[t][1]) * (1.0f / 128.0f);
}

// ---------- launcher ----------
extern "C" void kernel_launch(void* const* d_in, const int* in_sizes, int n_in,
                              void* d_out, int out_size, void* d_ws, size_t ws_size,
                              hipStream_t stream)
{
    const float* x_mid     = (const float*)d_in[0];   // [128,512,28,28]
    const float* x_deep    = (const float*)d_in[1];   // [128,2048,7,7]
    const float* w_shallow = (const float*)d_in[2];   // [2048,512]
    const float* ow1 = (const float*)d_in[3];         // [1024,2048]
    const float* ow2 = (const float*)d_in[4];         // [512,1024]
    const float* ow3 = (const float*)d_in[5];         // [64,512]
    const float* sw1 = (const float*)d_in[6];
    const float* sw2 = (const float*)d_in[7];
    const float* sw3 = (const float*)d_in[8];
    const float* tw1 = (const float*)d_in[9];
    const float* tw2 = (const float*)d_in[10];
    const float* cw1 = (const float*)d_in[11];
    const float* cw2 = (const float*)d_in[12];
    const float* qw1 = (const float*)d_in[13];
    const float* qw2 = (const float*)d_in[14];
    const float* center = (const float*)d_in[15];
    const float* proto  = (const float*)d_in[16];
    float* out = (float*)d_out;

    float* w = (float*)d_ws;
    float* xm_mean    = w;                 // 65536
    float* xd_mean    = w + 65536;         // 262144
    float* shallow_in = w + 327680;        // 262144
    float* o1 = w + 589824;                // 131072
    float* s1 = w + 720896;                // 131072
    float* o2 = w + 851968;                // 65536
    float* s2 = w + 917504;                // 65536
    float* o3 = w + 983040;                // 8192
    float* s3 = w + 991232;                // 8192
    float* ce_t = w + 999424;              // 128
    float* osv  = w + 999552;              // 128
    float* csv  = w + 999680;              // 128
    float* alv  = w + 999808;              // 128
    float* P    = w + 1000064;             // up to 2*8*131072 = 2097152 floats

    // A,B: the two big reductions
    mean_mid_kernel <<<16384, 256, 0, stream>>>(x_mid,  xm_mean);
    mean_deep_kernel<<<16384, 256, 0, stream>>>(x_deep, xd_mean);

    // C: shallow_in = xm_mean @ w_shallow^T  [128,2048], no activation
    gemm_nt_splitk<<<dim3(64, 4, 1), 256, 0, stream>>>(
        xm_mean, w_shallow, nullptr, nullptr, P, 2048, 512, 4);
    reduce_act<<<(262144 + 255) / 256, 256, 0, stream>>>(
        P, shallow_in, nullptr, 262144, 4, 1, 0);

    // D: layer 1 for both paths: [128,2048] -> [128,1024]
    gemm_nt_splitk<<<dim3(32, 8, 2), 256, 0, stream>>>(
        xd_mean, ow1, shallow_in, sw1, P, 1024, 2048, 8);
    reduce_act<<<(2 * 131072 + 255) / 256, 256, 0, stream>>>(
        P, o1, s1, 131072, 8, 2, 1);

    // E: layer 2: [128,1024] -> [128,512]
    gemm_nt_splitk<<<dim3(16, 8, 2), 256, 0, stream>>>(
        o1, ow2, s1, sw2, P, 512, 1024, 8);
    reduce_act<<<(2 * 65536 + 255) / 256, 256, 0, stream>>>(
        P, o2, s2, 65536, 8, 2, 1);

    // F: layer 3: [128,512] -> [128,64]
    gemm_nt_splitk<<<dim3(2, 8, 2), 256, 0, stream>>>(
        o2, ow3, s2, sw3, P, 64, 512, 8);
    reduce_act<<<(2 * 8192 + 255) / 256, 256, 0, stream>>>(
        P, o3, s3, 8192, 8, 2, 1);

    // tail + finalize
    tail_kernel<<<128, 64, 0, stream>>>(s3, o3, tw1, tw2, cw1, cw2, qw1, qw2,
                                        center, proto, ce_t, osv, csv, alv);
    finalize_kernel<<<1, 128, 0, stream>>>(ce_t, osv, csv, alv, out);
}